// Round 4
// baseline (175.060 us; speedup 1.0000x reference)
//
#include <hip/hip_runtime.h>
#include <math.h>

// Problem constants
#define Bsz 32
#define Nn  4096
#define DU  64
#define Dm  128

// workspace layout (float offsets)
#define WS_WKQ 0      // [2][128]  Wk-slice @ q per head
#define WS_BKQ 256    // [2]       bk-slice . q   (contiguous after WKQ)
#define WS_CNT 288    // [32] int  per-batch completion counters   <- memset 0
#define WS_A   320    // [32][2]   sum of alpha                    <- memset 0
#define WS_S   384    // [32][2][128] sum alpha*z                  <- memset 0
#define WS_WP  8576   // packed bf16 MFMA B-fragments: 48 frags * 64 lanes * 8 ushort

#define H1STR 136     // shorts per h1 LDS row (128 + 8 pad), 16B-aligned

typedef short frag_ab __attribute__((ext_vector_type(8)));
typedef float frag_cd __attribute__((ext_vector_type(4)));

__device__ __forceinline__ unsigned short f2bf(float x) {
    union { float f; unsigned int u; } c; c.f = x;
    unsigned int r = c.u + 0x7fffu + ((c.u >> 16) & 1u);   // RNE
    return (unsigned short)(r >> 16);
}

__device__ __forceinline__ float gelu_tanh(float x) {
    const float c0 = 0.7978845608028654f;
    const float c1 = 0.044715f;
    float y = c0 * (x + c1 * x * x * x);
    float t = __expf(-2.0f * fabsf(y));
    float th = (1.0f - t) / (1.0f + t);
    th = copysignf(th, y);
    return 0.5f * x * (1.0f + th);
}

// K0: 13 blocks. 0..11 pack W1/W2 into MFMA B-frag bf16 streams; 12 computes
// qv/wkq/bkq. (S/A/CNT zeroing is done by hipMemsetAsync in kernel_launch.)
__global__ __launch_bounds__(256) void precompute_kernel(
    const float* __restrict__ embed, const float* __restrict__ Wq,
    const float* __restrict__ bq, const float* __restrict__ Wk,
    const float* __restrict__ bk, const float* __restrict__ W1,
    const float* __restrict__ W2, float* __restrict__ ws)
{
    __shared__ float qv[128];
    const int tid = threadIdx.x;
    const int bid = blockIdx.x;

    if (bid < 12) {
        // B-frag layout: frag f, lane L (quad=L>>4, n=L&15) holds
        // B[ks*32 + quad*8 + j][nt*16 + n], j=0..7
        const int e = bid * 256 + tid;     // 0..3071
        const int f = e >> 6, L = e & 63;
        const int quad = L >> 4, n = L & 15;
        const float* src;
        int ks, nt;
        if (f < 16) { src = W1; ks = f >> 3;        nt = f & 7; }
        else        { src = W2; ks = (f - 16) >> 3; nt = (f - 16) & 7; }
        const int kb = ks * 32 + quad * 8;
        const int c  = nt * 16 + n;
        unsigned int p[4];
        #pragma unroll
        for (int jj = 0; jj < 4; ++jj) {
            unsigned int lo = f2bf(src[(kb + 2 * jj)     * Dm + c]);
            unsigned int hi = f2bf(src[(kb + 2 * jj + 1) * Dm + c]);
            p[jj] = lo | (hi << 16);
        }
        ((uint4*)(ws + WS_WP))[e] = make_uint4(p[0], p[1], p[2], p[3]);
    } else {
        if (tid < 128) {
            float s = bq[tid];
            #pragma unroll 8
            for (int j = 0; j < 128; ++j) s += embed[j] * Wq[j * 128 + tid];
            qv[tid] = s;
        }
        __syncthreads();
        if (tid < 128) {
            float s0 = 0.f, s1 = 0.f;
            #pragma unroll 8
            for (int dh = 0; dh < 64; ++dh) {
                s0 += Wk[tid * 128 + dh]      * qv[dh];
                s1 += Wk[tid * 128 + 64 + dh] * qv[64 + dh];
            }
            ws[WS_WKQ + tid]       = s0;
            ws[WS_WKQ + 128 + tid] = s1;
        }
        if (tid < 2) {
            float s = 0.f;
            for (int dh = 0; dh < 64; ++dh) s += bk[tid * 64 + dh] * qv[tid * 64 + dh];
            ws[WS_BKQ + tid] = s;
        }
    }
}

// K1: bf16-MFMA fused MLP + alpha + S/A pooling + per-batch fused epilogue.
// 512 blocks x 256 thr; block = 256 rows (4 iters x 4 waves x 16 rows).
// No min-waves bound: let allocator exceed 128 arch VGPRs (R3: 128-cap spilled 32MB).
__global__ __launch_bounds__(256) void mlp_pool_kernel(
    const float* __restrict__ u,  const float* __restrict__ b1,
    const float* __restrict__ b2, const float* __restrict__ Wv,
    const float* __restrict__ bv, const float* __restrict__ Wo,
    const float* __restrict__ bo, float* __restrict__ ws,
    float* __restrict__ out)
{
    __shared__ short lds_w[48 * 512];        // 48 KB weight fragments
    __shared__ short lds_h1[4 * 16 * H1STR]; // per-wave 16 x 136 bf16 (reused by epilogue)
    __shared__ float lds_c[514];             // wkq[256], bkq[2], b1[128], b2[128]
    __shared__ int   do_epi;

    const int tid  = threadIdx.x;
    const int wave = tid >> 6;
    const int lane = tid & 63;
    const int quad = lane >> 4;
    const int n15  = lane & 15;

    // stage packed weights global(L2) -> LDS
    {
        const float4* src = (const float4*)(ws + WS_WP);
        float4* dst = (float4*)lds_w;
        #pragma unroll
        for (int i = 0; i < 12; ++i) dst[tid + 256 * i] = src[tid + 256 * i];
    }
    // stage broadcast constants -> LDS (frees ~32 persistent VGPRs vs R3)
    for (int i = tid; i < 514; i += 256) {
        float v;
        if (i < 258)      v = ws[i];            // WS_WKQ(256) + WS_BKQ(2)
        else if (i < 386) v = b1[i - 258];
        else              v = b2[i - 386];
        lds_c[i] = v;
    }
    __syncthreads();

    const int block_row = blockIdx.x << 8;   // 256 rows per block
    const int b = blockIdx.x >> 4;           // 16 blocks per batch
    short* h1w = lds_h1 + wave * 16 * H1STR;

    const float bkq0 = lds_c[256];
    const float bkq1 = lds_c[257];

    float s0p[8], s1p[8];
    #pragma unroll
    for (int nt = 0; nt < 8; ++nt) { s0p[nt] = 0.f; s1p[nt] = 0.f; }
    float aA0 = 0.f, aA1 = 0.f;

    // prefetch u for iteration 0: lane (quad,n15) = row n15, k quad*8..+8 and +32
    const float* ubase = u + (size_t)(block_row + wave * 16 + n15) * DU + quad * 8;
    float4 f0 = *(const float4*)(ubase);
    float4 f1 = *(const float4*)(ubase + 4);
    float4 f2 = *(const float4*)(ubase + 32);
    float4 f3 = *(const float4*)(ubase + 36);

    #pragma unroll 1            // keep rolled: full unroll spilled in R2
    for (int it = 0; it < 4; ++it) {
        frag_ab a0, a1;
        a0[0] = (short)f2bf(f0.x); a0[1] = (short)f2bf(f0.y);
        a0[2] = (short)f2bf(f0.z); a0[3] = (short)f2bf(f0.w);
        a0[4] = (short)f2bf(f1.x); a0[5] = (short)f2bf(f1.y);
        a0[6] = (short)f2bf(f1.z); a0[7] = (short)f2bf(f1.w);
        a1[0] = (short)f2bf(f2.x); a1[1] = (short)f2bf(f2.y);
        a1[2] = (short)f2bf(f2.z); a1[3] = (short)f2bf(f2.w);
        a1[4] = (short)f2bf(f3.x); a1[5] = (short)f2bf(f3.y);
        a1[6] = (short)f2bf(f3.z); a1[7] = (short)f2bf(f3.w);

        // prefetch next iteration's u (in flight across MFMA/gelu below)
        if (it < 3) {
            const float* un = ubase + (size_t)((it + 1) * 64) * DU;
            f0 = *(const float4*)(un);
            f1 = *(const float4*)(un + 4);
            f2 = *(const float4*)(un + 32);
            f3 = *(const float4*)(un + 36);
        }

        // ---- layer 1: h1 = gelu(u @ W1 + b1), M16 N128 K64
        frag_cd acc[8];
        #pragma unroll
        for (int nt = 0; nt < 8; ++nt) acc[nt] = (frag_cd){0.f, 0.f, 0.f, 0.f};
        #pragma unroll
        for (int nt = 0; nt < 8; ++nt) {
            frag_ab w0 = *(const frag_ab*)&lds_w[(nt)     * 512 + lane * 8];
            acc[nt] = __builtin_amdgcn_mfma_f32_16x16x32_bf16(a0, w0, acc[nt], 0, 0, 0);
            frag_ab w1 = *(const frag_ab*)&lds_w[(8 + nt) * 512 + lane * 8];
            acc[nt] = __builtin_amdgcn_mfma_f32_16x16x32_bf16(a1, w1, acc[nt], 0, 0, 0);
        }

        // bias + gelu (fp32) -> h1 bf16 in wave-private LDS [m][H1STR]
        // D layout: row = quad*4+reg, col = nt*16+n15
        #pragma unroll
        for (int nt = 0; nt < 8; ++nt) {
            const float b1n = lds_c[258 + nt * 16 + n15];
            #pragma unroll
            for (int r = 0; r < 4; ++r) {
                float g = gelu_tanh(acc[nt][r] + b1n);
                h1w[(quad * 4 + r) * H1STR + nt * 16 + n15] = (short)f2bf(g);
            }
        }
        // no barrier: wave-private region, per-wave DS ordering

        // ---- layer 2: z = gelu(h1 @ W2 + b2), M16 N128 K128
        frag_cd acc2[8];
        #pragma unroll
        for (int nt = 0; nt < 8; ++nt) acc2[nt] = (frag_cd){0.f, 0.f, 0.f, 0.f};
        #pragma unroll
        for (int ks = 0; ks < 4; ++ks) {
            frag_ab a2 = *(const frag_ab*)&h1w[n15 * H1STR + ks * 32 + quad * 8];
            #pragma unroll
            for (int nt = 0; nt < 8; ++nt) {
                frag_ab w2f = *(const frag_ab*)&lds_w[(16 + ks * 8 + nt) * 512 + lane * 8];
                acc2[nt] = __builtin_amdgcn_mfma_f32_16x16x32_bf16(a2, w2f, acc2[nt], 0, 0, 0);
            }
        }

        // bias + gelu -> z fp32 in registers
        #pragma unroll
        for (int nt = 0; nt < 8; ++nt) {
            const float b2n = lds_c[386 + nt * 16 + n15];
            #pragma unroll
            for (int r = 0; r < 4; ++r)
                acc2[nt][r] = gelu_tanh(acc2[nt][r] + b2n);
        }

        // ---- alpha[r][h] = z[r,:] . wkq[h] + bkq[h] (reduce over n15 lanes)
        float p0[4], p1[4];
        #pragma unroll
        for (int r = 0; r < 4; ++r) { p0[r] = 0.f; p1[r] = 0.f; }
        #pragma unroll
        for (int nt = 0; nt < 8; ++nt) {
            const float w0n = lds_c[nt * 16 + n15];
            const float w1n = lds_c[128 + nt * 16 + n15];
            #pragma unroll
            for (int r = 0; r < 4; ++r) {
                p0[r] += acc2[nt][r] * w0n;
                p1[r] += acc2[nt][r] * w1n;
            }
        }
        #pragma unroll
        for (int r = 0; r < 4; ++r) {
            #pragma unroll
            for (int d = 1; d < 16; d <<= 1) {
                p0[r] += __shfl_xor(p0[r], d);
                p1[r] += __shfl_xor(p1[r], d);
            }
            p0[r] += bkq0;
            p1[r] += bkq1;
        }

        // ---- accumulate S and A
        #pragma unroll
        for (int nt = 0; nt < 8; ++nt) {
            #pragma unroll
            for (int r = 0; r < 4; ++r) {
                s0p[nt] += p0[r] * acc2[nt][r];
                s1p[nt] += p1[r] * acc2[nt][r];
            }
        }
        #pragma unroll
        for (int r = 0; r < 4; ++r) { aA0 += p0[r]; aA1 += p1[r]; }
    }

    // cross-quad reduce (quads hold disjoint rows), one atomic batch per wave
    #pragma unroll
    for (int nt = 0; nt < 8; ++nt) {
        s0p[nt] += __shfl_xor(s0p[nt], 16); s0p[nt] += __shfl_xor(s0p[nt], 32);
        s1p[nt] += __shfl_xor(s1p[nt], 16); s1p[nt] += __shfl_xor(s1p[nt], 32);
    }
    aA0 += __shfl_xor(aA0, 16); aA0 += __shfl_xor(aA0, 32);
    aA1 += __shfl_xor(aA1, 16); aA1 += __shfl_xor(aA1, 32);

    if (quad == 0) {
        #pragma unroll
        for (int nt = 0; nt < 8; ++nt) {
            const int c = nt * 16 + n15;
            atomicAdd(&ws[WS_S + (b * 2 + 0) * 128 + c], s0p[nt]);
            atomicAdd(&ws[WS_S + (b * 2 + 1) * 128 + c], s1p[nt]);
        }
    }
    if (lane == 0) {
        atomicAdd(&ws[WS_A + b * 2 + 0], aA0);
        atomicAdd(&ws[WS_A + b * 2 + 1], aA1);
    }

    // ---- per-batch completion counter; 16th finisher runs this batch's epilogue
    __syncthreads();                 // all waves' atomics drained (vmcnt(0) pre-barrier)
    if (tid == 0) {
        __threadfence();             // S/A atomics globally visible before counter inc
        int old = atomicAdd((int*)ws + WS_CNT + b, 1);
        do_epi = (old == 15) ? 1 : 0;
    }
    __syncthreads();

    if (do_epi) {
        // reuse lds_h1 as float scratch: sS[256], sA[2], pooled[128], part[256]
        float* eb      = (float*)lds_h1;
        float* e_sS    = eb;
        float* e_sA    = eb + 256;
        float* e_pool  = eb + 264;
        float* e_part  = eb + 392;

        // device-coherent reads of accumulators (atomic RMW bypasses stale L1/L2)
        e_sS[tid] = atomicAdd(&ws[WS_S + b * 256 + tid], 0.f);
        if (tid < 2) e_sA[tid] = atomicAdd(&ws[WS_A + b * 2 + tid], 0.f);
        __syncthreads();

        const int i = tid & 127, hf = tid >> 7;
        const int h = i >> 6;
        float dot = 0.f;
        #pragma unroll 8
        for (int d0 = 0; d0 < 64; ++d0) {
            const int d = hf * 64 + d0;
            dot += e_sS[h * 128 + d] * Wv[d * 128 + i];
        }
        e_part[tid] = dot;
        __syncthreads();
        if (tid < 128)
            e_pool[i] = (e_part[i] + e_part[128 + i] + e_sA[h] * bv[i]) * (1.0f / 4096.0f);
        __syncthreads();

        float o = 0.f;
        #pragma unroll 8
        for (int d0 = 0; d0 < 64; ++d0) {
            const int d = hf * 64 + d0;
            o += e_pool[d] * Wo[d * 128 + i];
        }
        e_part[tid] = o;
        __syncthreads();
        if (tid < 128)
            out[b * 128 + i] = bo[i] + e_part[i] + e_part[128 + i];
    }
}

extern "C" void kernel_launch(void* const* d_in, const int* in_sizes, int n_in,
                              void* d_out, int out_size, void* d_ws, size_t ws_size,
                              hipStream_t stream) {
    const float* u     = (const float*)d_in[0];
    // d_in[1] = x : unused by the reference
    const float* W1    = (const float*)d_in[2];
    const float* b1    = (const float*)d_in[3];
    const float* W2    = (const float*)d_in[4];
    const float* b2    = (const float*)d_in[5];
    const float* embed = (const float*)d_in[6];
    const float* Wq    = (const float*)d_in[7];
    const float* bq    = (const float*)d_in[8];
    const float* Wk    = (const float*)d_in[9];
    const float* bk    = (const float*)d_in[10];
    const float* Wv    = (const float*)d_in[11];
    const float* bv    = (const float*)d_in[12];
    const float* Wo    = (const float*)d_in[13];
    const float* bo    = (const float*)d_in[14];
    float* ws  = (float*)d_ws;
    float* out = (float*)d_out;

    // zero CNT + A + S (floats 288..8575)
    hipMemsetAsync((char*)d_ws + WS_CNT * 4, 0, (WS_WP - WS_CNT) * 4, stream);
    hipLaunchKernelGGL(precompute_kernel, dim3(13), dim3(256), 0, stream,
                       embed, Wq, bq, Wk, bk, W1, W2, ws);
    hipLaunchKernelGGL(mlp_pool_kernel, dim3(512), dim3(256), 0, stream,
                       u, b1, b2, Wv, bv, Wo, bo, ws, out);
}